// Round 11
// baseline (1364.891 us; speedup 1.0000x reference)
//
#include <hip/hip_runtime.h>
#include <math.h>

#define NROW 32768
#define DIM  1024
#define PDIM 256
#define NSEC 4
#define NCODE 1024
#define SECD 64

// ============================================================================
// K1: proj = (X + bias) @ W, exact OpenBLAS order, K split at 384/768 into
// 3 independent fmaf-chain segments (blockIdx.z); rn-add folds happen in
// k_comb as ((s0+s1)+s2). 64x256 tile, 256 thr, 8x8 micro, 4 waves/SIMD.
// ============================================================================
__global__ __launch_bounds__(256, 4) void k_proj(const float* __restrict__ X,
                                                 const float* __restrict__ W,
                                                 const float* __restrict__ bias,
                                                 float* __restrict__ p0) {
    __shared__ __align__(16) float As[16][68];   // As[k][row], pad 68: writes 2-way (free)
    __shared__ __align__(16) float Bs[16][256];  // linear (global_load_lds dest)
    const int t  = threadIdx.x;
    const int ry = t >> 5;            // 0..7 -> rows ry*8..+7
    const int rx = t & 31;            // col-group -> cols rx*8..+7
    const int rb = blockIdx.x * 64;
    const int z  = blockIdx.z;
    const int k0 = z * 384;
    const int kn = (z == 2) ? 256 : 384;
    const int lr = t >> 2;            // A-stage row 0..63
    const int ks = (t & 3) * 4;       // A-stage k offset
    const int wv = t >> 6;
    const int ln = t & 63;
    // lane ln writes LDS granule ln; source granule: ln<32 -> 2*ln, else 2*(ln-32)+1
    const int gsw = ((ln & 31) << 1) | (ln >> 5);
    float* outp = p0 + (size_t)z * ((size_t)NROW * PDIM);
    float acc[8][8] = {};
    for (int kc = k0; kc < k0 + kn; kc += 16) {
        #pragma unroll
        for (int j = 0; j < 4; ++j) {
            const int krow = wv * 4 + j;
            __builtin_amdgcn_global_load_lds(
                (const __attribute__((address_space(1))) void*)(W + (size_t)(kc + krow) * PDIM + gsw * 4),
                (__attribute__((address_space(3))) void*)(&Bs[krow][0]),
                16, 0, 0);
        }
        float4 a = *(const float4*)&X[(size_t)(rb + lr) * DIM + kc + ks];
        float4 c = *(const float4*)&bias[kc + ks];
        As[ks + 0][lr] = a.x + c.x;
        As[ks + 1][lr] = a.y + c.y;
        As[ks + 2][lr] = a.z + c.z;
        As[ks + 3][lr] = a.w + c.w;
        __syncthreads();   // drains vmcnt (global_load_lds) + lgkmcnt (ds writes)
        #pragma unroll
        for (int k = 0; k < 16; ++k) {
            float4 x0 = *(const float4*)&As[k][ry * 8];
            float4 x1 = *(const float4*)&As[k][ry * 8 + 4];
            float4 y0 = *(const float4*)&Bs[k][rx * 4];         // cols rx*8..+3
            float4 y1 = *(const float4*)&Bs[k][128 + rx * 4];   // cols rx*8+4..+7
            float aa[8] = {x0.x, x0.y, x0.z, x0.w, x1.x, x1.y, x1.z, x1.w};
            float bb[8] = {y0.x, y0.y, y0.z, y0.w, y1.x, y1.y, y1.z, y1.w};
            #pragma unroll
            for (int i = 0; i < 8; ++i)
                #pragma unroll
                for (int j = 0; j < 8; ++j)
                    acc[i][j] = fmaf(aa[i], bb[j], acc[i][j]);
        }
        __syncthreads();
    }
    #pragma unroll
    for (int i = 0; i < 8; ++i) {
        const size_t base = (size_t)(rb + ry * 8 + i) * PDIM + rx * 8;
        *(float4*)&outp[base]     = make_float4(acc[i][0], acc[i][1], acc[i][2], acc[i][3]);
        *(float4*)&outp[base + 4] = make_float4(acc[i][4], acc[i][5], acc[i][6], acc[i][7]);
    }
}

// proj[i] = ((s0 + s1) + s2), rn adds — bit-identical to the original fold.
__global__ __launch_bounds__(256) void k_comb(float* __restrict__ p) {
    const size_t i = ((size_t)blockIdx.x * 256 + threadIdx.x) * 4;
    float4 a = *(const float4*)&p[i];
    float4 b = *(const float4*)&p[i + 8388608];
    float4 c = *(const float4*)&p[i + 16777216];
    float4 r;
    r.x = __fadd_rn(__fadd_rn(a.x, b.x), c.x);
    r.y = __fadd_rn(__fadd_rn(a.y, b.y), c.y);
    r.z = __fadd_rn(__fadd_rn(a.z, b.z), c.z);
    r.w = __fadd_rn(__fadd_rn(a.w, b.w), c.w);
    *(float4*)&p[i] = r;
}

// ============================================================================
// K_pm: PM = proj @ M (M = W^T W), tolerant numerics. Same 64x256 template,
// K=256 split into 2 z-halves; halves summed inside k_rowres (no combine).
// ============================================================================
__global__ __launch_bounds__(256, 4) void k_pm(const float* __restrict__ P,
                                               const float* __restrict__ M,
                                               float* __restrict__ PMa,
                                               float* __restrict__ PMb) {
    __shared__ __align__(16) float As[16][68];
    __shared__ __align__(16) float Bs[16][256];
    const int t  = threadIdx.x;
    const int ry = t >> 5;
    const int rx = t & 31;
    const int rb = blockIdx.x * 64;
    const int z  = blockIdx.z;
    const int k0 = z * 128;
    const int lr = t >> 2;
    const int ks = (t & 3) * 4;
    const int wv = t >> 6;
    const int ln = t & 63;
    const int gsw = ((ln & 31) << 1) | (ln >> 5);
    float* outp = z ? PMb : PMa;
    float acc[8][8] = {};
    for (int kc = k0; kc < k0 + 128; kc += 16) {
        #pragma unroll
        for (int j = 0; j < 4; ++j) {
            const int krow = wv * 4 + j;
            __builtin_amdgcn_global_load_lds(
                (const __attribute__((address_space(1))) void*)(M + (size_t)(kc + krow) * PDIM + gsw * 4),
                (__attribute__((address_space(3))) void*)(&Bs[krow][0]),
                16, 0, 0);
        }
        float4 a = *(const float4*)&P[(size_t)(rb + lr) * PDIM + kc + ks];
        As[ks + 0][lr] = a.x;
        As[ks + 1][lr] = a.y;
        As[ks + 2][lr] = a.z;
        As[ks + 3][lr] = a.w;
        __syncthreads();
        #pragma unroll
        for (int k = 0; k < 16; ++k) {
            float4 x0 = *(const float4*)&As[k][ry * 8];
            float4 x1 = *(const float4*)&As[k][ry * 8 + 4];
            float4 y0 = *(const float4*)&Bs[k][rx * 4];
            float4 y1 = *(const float4*)&Bs[k][128 + rx * 4];
            float aa[8] = {x0.x, x0.y, x0.z, x0.w, x1.x, x1.y, x1.z, x1.w};
            float bb[8] = {y0.x, y0.y, y0.z, y0.w, y1.x, y1.y, y1.z, y1.w};
            #pragma unroll
            for (int i = 0; i < 8; ++i)
                #pragma unroll
                for (int j = 0; j < 8; ++j)
                    acc[i][j] = fmaf(aa[i], bb[j], acc[i][j]);
        }
        __syncthreads();
    }
    #pragma unroll
    for (int i = 0; i < 8; ++i) {
        const size_t base = (size_t)(rb + ry * 8 + i) * PDIM + rx * 8;
        *(float4*)&outp[base]     = make_float4(acc[i][0], acc[i][1], acc[i][2], acc[i][3]);
        *(float4*)&outp[base + 4] = make_float4(acc[i][4], acc[i][5], acc[i][6], acc[i][7]);
    }
}

// ============================================================================
// K_wtw: M[256][256] = W^T W  (K=1024). 64x64 tile, 4x4 micro, grid (4,4).
// ============================================================================
__global__ __launch_bounds__(256) void k_wtw(const float* __restrict__ W,
                                             float* __restrict__ M) {
    __shared__ float As[16][64];
    __shared__ float Bs[16][64];
    const int t = threadIdx.x;
    const int tx = t & 15, ty = t >> 4;
    const int ib = blockIdx.x * 64;
    const int jb = blockIdx.y * 64;
    const int sk = t >> 4;
    const int sc = (t & 15) * 4;
    float acc[4][4] = {};
    for (int kc = 0; kc < DIM; kc += 16) {
        float4 a = *(const float4*)&W[(size_t)(kc + sk) * PDIM + ib + sc];
        float4 b = *(const float4*)&W[(size_t)(kc + sk) * PDIM + jb + sc];
        *(float4*)&As[sk][sc] = a;
        *(float4*)&Bs[sk][sc] = b;
        __syncthreads();
        #pragma unroll
        for (int k = 0; k < 16; ++k) {
            float4 a4 = *(const float4*)&As[k][ty * 4];
            float4 b4 = *(const float4*)&Bs[k][tx * 4];
            float aa[4] = {a4.x, a4.y, a4.z, a4.w};
            float bb[4] = {b4.x, b4.y, b4.z, b4.w};
            #pragma unroll
            for (int i = 0; i < 4; ++i)
                #pragma unroll
                for (int j = 0; j < 4; ++j)
                    acc[i][j] = fmaf(aa[i], bb[j], acc[i][j]);
        }
        __syncthreads();
    }
    #pragma unroll
    for (int i = 0; i < 4; ++i)
        #pragma unroll
        for (int j = 0; j < 4; ++j)
            M[(size_t)(ib + ty * 4 + i) * PDIM + jb + tx * 4 + j] = acc[i][j];
}

// xn2[n] = ||x_n + bias||^2   (memory-bound pass over X)
__global__ __launch_bounds__(256) void k_xn2(const float* __restrict__ X,
                                             const float* __restrict__ bias,
                                             float* __restrict__ xn2) {
    const int n = blockIdx.x * 4 + (threadIdx.x >> 6);
    const int lane = threadIdx.x & 63;
    float s = 0.0f;
    #pragma unroll
    for (int i = 0; i < 4; ++i) {
        float4 x = *(const float4*)&X[(size_t)n * DIM + i * 256 + lane * 4];
        float4 b = *(const float4*)&bias[i * 256 + lane * 4];
        float vx = x.x + b.x, vy = x.y + b.y, vz = x.z + b.z, vw = x.w + b.w;
        s = fmaf(vx, vx, s); s = fmaf(vy, vy, s);
        s = fmaf(vz, vz, s); s = fmaf(vw, vw, s);
    }
    #pragma unroll
    for (int o = 1; o < 64; o <<= 1) s += __shfl_xor(s, o);
    if (lane == 0) xn2[n] = s;
}

// rowres[n] = xn2[n] + sum_c P[n][c]*((PMa[n][c]+PMb[n][c]) - 2*P[n][c])
__global__ __launch_bounds__(256) void k_rowres(const float* __restrict__ P,
                                                const float* __restrict__ PMa,
                                                const float* __restrict__ PMb,
                                                const float* __restrict__ xn2,
                                                float* __restrict__ rowres) {
    const int n = blockIdx.x * 4 + (threadIdx.x >> 6);
    const int lane = threadIdx.x & 63;
    float4 p  = *(const float4*)&P[(size_t)n * PDIM + lane * 4];
    float4 pa = *(const float4*)&PMa[(size_t)n * PDIM + lane * 4];
    float4 pb = *(const float4*)&PMb[(size_t)n * PDIM + lane * 4];
    float s = 0.0f;
    s = fmaf(p.x, (pa.x + pb.x) - 2.0f * p.x, s);
    s = fmaf(p.y, (pa.y + pb.y) - 2.0f * p.y, s);
    s = fmaf(p.z, (pa.z + pb.z) - 2.0f * p.z, s);
    s = fmaf(p.w, (pa.w + pb.w) - 2.0f * p.w, s);
    #pragma unroll
    for (int o = 1; o < 64; o <<= 1) s += __shfl_xor(s, o);
    if (lane == 0) rowres[n] = xn2[n] + s;
}

// ============================================================================
// K2: cov += P^T P (fp32, split-K x64, atomicAdd) — tolerant.
// ============================================================================
__global__ __launch_bounds__(256) void k_cov(const float* __restrict__ Pm,
                                             float* __restrict__ cov) {
    __shared__ float As[16][64];
    __shared__ float Bs[16][64];
    const int t = threadIdx.x;
    const int tx = t & 15, ty = t >> 4;
    const int ib = blockIdx.x * 64;
    const int jb = blockIdx.y * 64;
    const int nb = blockIdx.z * 512;
    const int sk = t >> 4;
    const int sc = (t & 15) * 4;
    float acc[4][4] = {};
    for (int kc = 0; kc < 512; kc += 16) {
        float4 a = *(const float4*)&Pm[(size_t)(nb + kc + sk) * PDIM + ib + sc];
        float4 b = *(const float4*)&Pm[(size_t)(nb + kc + sk) * PDIM + jb + sc];
        *(float4*)&As[sk][sc] = a;
        *(float4*)&Bs[sk][sc] = b;
        __syncthreads();
        #pragma unroll
        for (int k = 0; k < 16; ++k) {
            float4 a4 = *(const float4*)&As[k][ty * 4];
            float4 b4 = *(const float4*)&Bs[k][tx * 4];
            float aa[4] = {a4.x, a4.y, a4.z, a4.w};
            float bb[4] = {b4.x, b4.y, b4.z, b4.w};
            #pragma unroll
            for (int i = 0; i < 4; ++i)
                #pragma unroll
                for (int j = 0; j < 4; ++j)
                    acc[i][j] = fmaf(aa[i], bb[j], acc[i][j]);
        }
        __syncthreads();
    }
    #pragma unroll
    for (int i = 0; i < 4; ++i)
        #pragma unroll
        for (int j = 0; j < 4; ++j)
            atomicAdd(&cov[(size_t)(ib + ty * 4 + i) * PDIM + jb + tx * 4 + j], acc[i][j]);
}

__global__ __launch_bounds__(256) void k_covloss(const float* __restrict__ cov,
                                                 float* __restrict__ scal) {
    const int t = threadIdx.x;
    float s = 0.0f;
    for (int e = t; e < PDIM * PDIM; e += 256) {
        int i = e >> 8, j = e & 255;
        float v = cov[e] * (1.0f / 32768.0f) - (i == j ? 1.0f : 0.0f);
        s = fmaf(v, v, s);
    }
    #pragma unroll
    for (int o = 1; o < 64; o <<= 1) s += __shfl_xor(s, o);
    __shared__ float r4[4];
    if ((t & 63) == 0) r4[t >> 6] = s;
    __syncthreads();
    if (t == 0) scal[1] = (r4[0] + r4[1] + r4[2] + r4[3]) * (1.0f / 65536.0f);
}

// l2 sum: scal[0] += sum over rows of sqrt(rowres)
__global__ __launch_bounds__(256) void k_l2(const float* __restrict__ rowres,
                                            float* __restrict__ scal) {
    int r = blockIdx.x * 256 + threadIdx.x;
    float v = sqrtf(rowres[r]);
    #pragma unroll
    for (int o = 1; o < 64; o <<= 1) v += __shfl_xor(v, o);
    if ((threadIdx.x & 63) == 0) atomicAdd(&scal[0], v);
}

// cnorm: numpy pairwise (8-acc) order, exact
__global__ __launch_bounds__(256) void k_cnorm(const float* __restrict__ cbs,
                                               float* __restrict__ cnorm) {
    int c = blockIdx.x * 256 + threadIdx.x;
    const float* p = &cbs[(size_t)c * SECD];
    float a[8];
    #pragma unroll
    for (int j = 0; j < 8; ++j) a[j] = __fmul_rn(p[j], p[j]);
    #pragma unroll
    for (int i = 8; i < 64; i += 8)
        #pragma unroll
        for (int j = 0; j < 8; ++j)
            a[j] = __fadd_rn(a[j], __fmul_rn(p[i + j], p[i + j]));
    float r = __fadd_rn(__fadd_rn(__fadd_rn(a[0], a[1]), __fadd_rn(a[2], a[3])),
                        __fadd_rn(__fadd_rn(a[4], a[5]), __fadd_rn(a[6], a[7])));
    cnorm[c] = r;
}

// ============================================================================
// K4: VQ, exact argmin. One row per lane in 64 VGPRs; codebook read at
// wave-UNIFORM addresses (blockIdx.y + loop constants only) -> hipcc emits
// s_load into SGPRs; inner fma is v_fma(vX, sC, vAcc) — zero LDS, zero
// vector-mem in the hot loop. Lane scans all 1024 codes ascending with
// first-min (= numpy argmin); fmaf chain per (row,code) k-ascending —
// bit-identical distances to the round-2/3 passing kernels. No barriers.
// ============================================================================
__global__ __launch_bounds__(64) void k_vq(const float* __restrict__ proj,
                                           const float* __restrict__ cbs,
                                           const float* __restrict__ cnorm,
                                           int* __restrict__ widx,
                                           float* __restrict__ out_idx,
                                           float* __restrict__ qpart) {
    const int ln  = threadIdx.x;      // 0..63, one row per lane
    const int s   = blockIdx.y;       // section
    const int row = blockIdx.x * 64 + ln;

    // lane's x-row into registers (per-lane contiguous 256B: 4 lines, used fully)
    float x[64];
    {
        const float* xr = &proj[(size_t)row * PDIM + s * SECD];
        #pragma unroll
        for (int i = 0; i < 64; i += 4) {
            float4 v = *(const float4*)&xr[i];
            x[i] = v.x; x[i + 1] = v.y; x[i + 2] = v.z; x[i + 3] = v.w;
        }
    }
    // xnorm: numpy pairwise_sum(64), 8 accumulators, no fma — exact
    float a8[8];
    #pragma unroll
    for (int j = 0; j < 8; ++j) a8[j] = __fmul_rn(x[j], x[j]);
    #pragma unroll
    for (int i = 8; i < 64; i += 8)
        #pragma unroll
        for (int j = 0; j < 8; ++j)
            a8[j] = __fadd_rn(a8[j], __fmul_rn(x[i + j], x[i + j]));
    const float xn = __fadd_rn(__fadd_rn(__fadd_rn(a8[0], a8[1]), __fadd_rn(a8[2], a8[3])),
                               __fadd_rn(__fadd_rn(a8[4], a8[5]), __fadd_rn(a8[6], a8[7])));

    const float* cb = &cbs[(size_t)s * NCODE * SECD];   // uniform base
    const float* cn = &cnorm[s * NCODE];                // uniform base

    float best = 3.4e38f; int bcode = 0;
    #pragma unroll 1
    for (int c0 = 0; c0 < NCODE; c0 += 8) {
        float acc[8] = {};
        #pragma unroll
        for (int kk = 0; kk < 64; kk += 4) {
            #pragma unroll
            for (int j = 0; j < 8; ++j) {
                // uniform address -> s_load_dwordx4; SGPR operand feeds v_fma
                float4 c4 = *(const float4*)&cb[(size_t)(c0 + j) * SECD + kk];
                acc[j] = fmaf(x[kk],     c4.x, acc[j]);
                acc[j] = fmaf(x[kk + 1], c4.y, acc[j]);
                acc[j] = fmaf(x[kk + 2], c4.z, acc[j]);
                acc[j] = fmaf(x[kk + 3], c4.w, acc[j]);
            }
        }
        #pragma unroll
        for (int j = 0; j < 8; ++j) {
            float d = __fadd_rn(__fsub_rn(xn, __fmul_rn(2.0f, acc[j])), cn[c0 + j]);
            if (d < best) { best = d; bcode = c0 + j; }   // first-min = numpy argmin
        }
    }
    widx[s * NROW + row] = bcode;
    out_idx[s * NROW + row] = (float)bcode;
    // qloss partial: (q - x)^2 per dim (per-lane gather of winning code)
    const float* crow = &cb[(size_t)bcode * SECD];
    #pragma unroll
    for (int i = 0; i < 64; i += 4) {
        float4 q = *(const float4*)&crow[i];
        float d0 = q.x - x[i],     d1 = q.y - x[i + 1];
        float d2 = q.z - x[i + 2], d3 = q.w - x[i + 3];
        *(float4*)&qpart[((size_t)s * NROW + row) * SECD + i] =
            make_float4(__fmul_rn(d0, d0), __fmul_rn(d1, d1),
                        __fmul_rn(d2, d2), __fmul_rn(d3, d3));
    }
}

// ============================================================================
// K5: CbU[s][c][d] = sum_k Cb[s][c][k] * W[d][s*64+k]
// ============================================================================
__global__ __launch_bounds__(256) void k_cbu(const float* __restrict__ cbs,
                                             const float* __restrict__ W,
                                             float* __restrict__ cbu) {
    __shared__ float As[16][64];
    __shared__ float Bs[16][64];
    const int t = threadIdx.x;
    const int tx = t & 15, ty = t >> 4;
    const int s = blockIdx.z;
    const int cbase = blockIdx.y * 64;
    const int db = blockIdx.x * 64;
    const int lr = t >> 2;
    const int lk = (t & 3) * 4;
    float acc[4][4] = {};
    for (int kc = 0; kc < SECD; kc += 16) {
        float4 a = *(const float4*)&cbs[(size_t)(s * NCODE + cbase + lr) * SECD + kc + lk];
        float4 b = *(const float4*)&W[(size_t)(db + lr) * PDIM + s * SECD + kc + lk];
        As[lk + 0][lr] = a.x; As[lk + 1][lr] = a.y;
        As[lk + 2][lr] = a.z; As[lk + 3][lr] = a.w;
        Bs[lk + 0][lr] = b.x; Bs[lk + 1][lr] = b.y;
        Bs[lk + 2][lr] = b.z; Bs[lk + 3][lr] = b.w;
        __syncthreads();
        #pragma unroll
        for (int k = 0; k < 16; ++k) {
            float4 a4 = *(const float4*)&As[k][ty * 4];
            float4 b4 = *(const float4*)&Bs[k][tx * 4];
            float aa[4] = {a4.x, a4.y, a4.z, a4.w};
            float bb[4] = {b4.x, b4.y, b4.z, b4.w};
            #pragma unroll
            for (int i = 0; i < 4; ++i)
                #pragma unroll
                for (int j = 0; j < 4; ++j)
                    acc[i][j] = fmaf(aa[i], bb[j], acc[i][j]);
        }
        __syncthreads();
    }
    #pragma unroll
    for (int i = 0; i < 4; ++i) {
        float4 v = make_float4(acc[i][0], acc[i][1], acc[i][2], acc[i][3]);
        *(float4*)&cbu[(size_t)(s * NCODE + cbase + ty * 4 + i) * DIM + db + tx * 4] = v;
    }
}

// K6: out0[n][d] = sum_s CbU[s][idx[s][n]][d] - bias[d]
__global__ __launch_bounds__(256) void k_gather(const float* __restrict__ cbu,
                                                const int* __restrict__ widx,
                                                const float* __restrict__ bias,
                                                float* __restrict__ out0) {
    const int n = blockIdx.x;
    const int d = threadIdx.x * 4;
    int i0 = widx[0 * NROW + n];
    int i1 = widx[1 * NROW + n];
    int i2 = widx[2 * NROW + n];
    int i3 = widx[3 * NROW + n];
    float4 v0 = *(const float4*)&cbu[((size_t)(0 * NCODE + i0)) * DIM + d];
    float4 v1 = *(const float4*)&cbu[((size_t)(1 * NCODE + i1)) * DIM + d];
    float4 v2 = *(const float4*)&cbu[((size_t)(2 * NCODE + i2)) * DIM + d];
    float4 v3 = *(const float4*)&cbu[((size_t)(3 * NCODE + i3)) * DIM + d];
    float4 b = *(const float4*)&bias[d];
    float4 r;
    r.x = v0.x + v1.x + v2.x + v3.x - b.x;
    r.y = v0.y + v1.y + v2.y + v3.y - b.y;
    r.z = v0.z + v1.z + v2.z + v3.z - b.z;
    r.w = v0.w + v1.w + v2.w + v3.w - b.w;
    *(float4*)&out0[(size_t)n * DIM + d] = r;
}

// out1[e] = 0.25*(((q0+q1)+q2)+q3) + pca  — MUST run before k_gather
// (qpart lives inside the out0 region that k_gather overwrites).
__global__ __launch_bounds__(256) void k_addpca(float* __restrict__ out1,
                                                const float* __restrict__ qpart,
                                                const float* __restrict__ scal) {
    float pca = scal[0] * (1.0f / 32768.0f) + scal[1];
    const size_t e = ((size_t)blockIdx.x * 256 + threadIdx.x) * 4;
    float4 a = *(const float4*)&qpart[e];
    float4 b = *(const float4*)&qpart[e + 2097152];
    float4 c = *(const float4*)&qpart[e + 4194304];
    float4 d = *(const float4*)&qpart[e + 6291456];
    float4 r;
    r.x = 0.25f * __fadd_rn(__fadd_rn(__fadd_rn(a.x, b.x), c.x), d.x) + pca;
    r.y = 0.25f * __fadd_rn(__fadd_rn(__fadd_rn(a.y, b.y), c.y), d.y) + pca;
    r.z = 0.25f * __fadd_rn(__fadd_rn(__fadd_rn(a.z, b.z), c.z), d.z) + pca;
    r.w = 0.25f * __fadd_rn(__fadd_rn(__fadd_rn(a.w, b.w), c.w), d.w) + pca;
    *(float4*)&out1[e] = r;
}

__global__ __launch_bounds__(256) void k_tail(const float* __restrict__ cbs,
                                              float* __restrict__ out3,
                                              float* __restrict__ out4) {
    int e = blockIdx.x * 256 + threadIdx.x;
    ((float4*)out3)[e] = ((const float4*)cbs)[e];
    if (e < 4096) out4[e] = 1.0f;
}

extern "C" void kernel_launch(void* const* d_in, const int* in_sizes, int n_in,
                              void* d_out, int out_size, void* d_ws, size_t ws_size,
                              hipStream_t stream) {
    (void)in_sizes; (void)n_in; (void)out_size; (void)ws_size;
    const float* X    = (const float*)d_in[0];   // [32768,1024]
    const float* W    = (const float*)d_in[1];   // [1024,256]
    const float* bias = (const float*)d_in[2];   // [1024]
    const float* cbs  = (const float*)d_in[3];   // [4,1024,64]

    float* out  = (float*)d_out;
    float* out0 = out;                 // quantized [32768,1024]
    float* out1 = out + 33554432;      // qloss [32768,64]
    float* out2 = out + 35651584;      // nn_idx as float [4,32768]
    float* out3 = out + 35782656;      // codebook copy [4096,64]
    float* out4 = out + 36044800;      // cluster_counts ones [4,1024]

    char* ws = (char*)d_ws;
    float* cbu    = (float*)(ws);                  // 16777216 B
    float* rowres = (float*)(ws + 16777216);       //   131072 B
    float* cov    = (float*)(ws + 16908288);       //   262144 B
    float* scal   = (float*)(ws + 17170432);       //       64 B
    float* cnorm  = (float*)(ws + 17170496);       //    16384 B
    int*   widx   = (int*)  (ws + 17186880);       //   524288 B
    float* wtw    = (float*)(ws + 17711168);       //   262144 B (M = W^T W)

    // scratch inside the out0 region (dead before k_gather writes it):
    // p0/proj [0, 8388608), p1 [8388608, 16777216), p2 [16777216, 25165824)
    // PMb at [25165824, 33554432). After k_rowres, p1 region is reused as
    // qpart[4][32768][64]; k_addpca consumes it BEFORE k_gather clobbers out0.
    float* proj  = out0;                 // segment 0 accum -> combined proj
    float* PMa   = out0 + 8388608;       // p1, then PM half A
    float* PMb   = out0 + 25165824;      // PM half B
    float* qpart = out0 + 8388608;       // qloss partials (after PMa is dead)
    // xn2 lives in out1's region (out1 written later by k_addpca)
    float* xn2  = out1;                  // 32768 floats

    // zero cov + scal (contiguous)
    hipMemsetAsync(ws + 16908288, 0, 262144 + 64, stream);

    k_proj    <<<dim3(512, 1, 3), 256, 0, stream>>>(X, W, bias, proj);
    k_comb    <<<8192,            256, 0, stream>>>(proj);
    k_xn2     <<<8192,            256, 0, stream>>>(X, bias, xn2);
    k_wtw     <<<dim3(4, 4),      256, 0, stream>>>(W, wtw);
    k_cov     <<<dim3(4, 4, 64),  256, 0, stream>>>(proj, cov);
    k_covloss <<<1,               256, 0, stream>>>(cov, scal);
    k_pm      <<<dim3(512, 1, 2), 256, 0, stream>>>(proj, wtw, PMa, PMb);
    k_rowres  <<<8192,            256, 0, stream>>>(proj, PMa, PMb, xn2, rowres);
    k_l2      <<<128,             256, 0, stream>>>(rowres, scal);
    k_cnorm   <<<16,              256, 0, stream>>>(cbs, cnorm);
    k_vq      <<<dim3(512, 4),    64,  0, stream>>>(proj, cbs, cnorm, widx, out2, qpart);
    k_addpca  <<<2048,            256, 0, stream>>>(out1, qpart, scal);   // before k_gather!
    k_cbu     <<<dim3(16, 16, 4), 256, 0, stream>>>(cbs, W, cbu);
    k_gather  <<<32768,           256, 0, stream>>>(cbu, widx, bias, out0);
    k_tail    <<<256,             256, 0, stream>>>(cbs, out3, out4);
}

// Round 13
// 1069.108 us; speedup vs baseline: 1.2767x; 1.2767x over previous
//
#include <hip/hip_runtime.h>
#include <math.h>

#define NROW 32768
#define DIM  1024
#define PDIM 256
#define NSEC 4
#define NCODE 1024
#define SECD 64

// ============================================================================
// K1: proj = (X + bias) @ W, exact OpenBLAS order, K split at 384/768 into
// 3 independent fmaf-chain segments (blockIdx.z); rn-add folds happen in
// k_comb as ((s0+s1)+s2). 64x256 tile, 256 thr, 8x8 micro, 4 waves/SIMD.
// ============================================================================
__global__ __launch_bounds__(256, 4) void k_proj(const float* __restrict__ X,
                                                 const float* __restrict__ W,
                                                 const float* __restrict__ bias,
                                                 float* __restrict__ p0) {
    __shared__ __align__(16) float As[16][68];   // As[k][row], pad 68: writes 2-way (free)
    __shared__ __align__(16) float Bs[16][256];  // linear (global_load_lds dest)
    const int t  = threadIdx.x;
    const int ry = t >> 5;            // 0..7 -> rows ry*8..+7
    const int rx = t & 31;            // col-group -> cols rx*8..+7
    const int rb = blockIdx.x * 64;
    const int z  = blockIdx.z;
    const int k0 = z * 384;
    const int kn = (z == 2) ? 256 : 384;
    const int lr = t >> 2;            // A-stage row 0..63
    const int ks = (t & 3) * 4;       // A-stage k offset
    const int wv = t >> 6;
    const int ln = t & 63;
    // lane ln writes LDS granule ln; source granule: ln<32 -> 2*ln, else 2*(ln-32)+1
    const int gsw = ((ln & 31) << 1) | (ln >> 5);
    float* outp = p0 + (size_t)z * ((size_t)NROW * PDIM);
    float acc[8][8] = {};
    for (int kc = k0; kc < k0 + kn; kc += 16) {
        #pragma unroll
        for (int j = 0; j < 4; ++j) {
            const int krow = wv * 4 + j;
            __builtin_amdgcn_global_load_lds(
                (const __attribute__((address_space(1))) void*)(W + (size_t)(kc + krow) * PDIM + gsw * 4),
                (__attribute__((address_space(3))) void*)(&Bs[krow][0]),
                16, 0, 0);
        }
        float4 a = *(const float4*)&X[(size_t)(rb + lr) * DIM + kc + ks];
        float4 c = *(const float4*)&bias[kc + ks];
        As[ks + 0][lr] = a.x + c.x;
        As[ks + 1][lr] = a.y + c.y;
        As[ks + 2][lr] = a.z + c.z;
        As[ks + 3][lr] = a.w + c.w;
        __syncthreads();   // drains vmcnt (global_load_lds) + lgkmcnt (ds writes)
        #pragma unroll
        for (int k = 0; k < 16; ++k) {
            float4 x0 = *(const float4*)&As[k][ry * 8];
            float4 x1 = *(const float4*)&As[k][ry * 8 + 4];
            float4 y0 = *(const float4*)&Bs[k][rx * 4];         // cols rx*8..+3
            float4 y1 = *(const float4*)&Bs[k][128 + rx * 4];   // cols rx*8+4..+7
            float aa[8] = {x0.x, x0.y, x0.z, x0.w, x1.x, x1.y, x1.z, x1.w};
            float bb[8] = {y0.x, y0.y, y0.z, y0.w, y1.x, y1.y, y1.z, y1.w};
            #pragma unroll
            for (int i = 0; i < 8; ++i)
                #pragma unroll
                for (int j = 0; j < 8; ++j)
                    acc[i][j] = fmaf(aa[i], bb[j], acc[i][j]);
        }
        __syncthreads();
    }
    #pragma unroll
    for (int i = 0; i < 8; ++i) {
        const size_t base = (size_t)(rb + ry * 8 + i) * PDIM + rx * 8;
        *(float4*)&outp[base]     = make_float4(acc[i][0], acc[i][1], acc[i][2], acc[i][3]);
        *(float4*)&outp[base + 4] = make_float4(acc[i][4], acc[i][5], acc[i][6], acc[i][7]);
    }
}

// proj[i] = ((s0 + s1) + s2), rn adds — bit-identical to the original fold.
__global__ __launch_bounds__(256) void k_comb(float* __restrict__ p) {
    const size_t i = ((size_t)blockIdx.x * 256 + threadIdx.x) * 4;
    float4 a = *(const float4*)&p[i];
    float4 b = *(const float4*)&p[i + 8388608];
    float4 c = *(const float4*)&p[i + 16777216];
    float4 r;
    r.x = __fadd_rn(__fadd_rn(a.x, b.x), c.x);
    r.y = __fadd_rn(__fadd_rn(a.y, b.y), c.y);
    r.z = __fadd_rn(__fadd_rn(a.z, b.z), c.z);
    r.w = __fadd_rn(__fadd_rn(a.w, b.w), c.w);
    *(float4*)&p[i] = r;
}

// ============================================================================
// K_pm: PM = proj @ M (M = W^T W), tolerant numerics. Same 64x256 template,
// K=256 split into 2 z-halves; halves summed inside k_rowres (no combine).
// ============================================================================
__global__ __launch_bounds__(256, 4) void k_pm(const float* __restrict__ P,
                                               const float* __restrict__ M,
                                               float* __restrict__ PMa,
                                               float* __restrict__ PMb) {
    __shared__ __align__(16) float As[16][68];
    __shared__ __align__(16) float Bs[16][256];
    const int t  = threadIdx.x;
    const int ry = t >> 5;
    const int rx = t & 31;
    const int rb = blockIdx.x * 64;
    const int z  = blockIdx.z;
    const int k0 = z * 128;
    const int lr = t >> 2;
    const int ks = (t & 3) * 4;
    const int wv = t >> 6;
    const int ln = t & 63;
    const int gsw = ((ln & 31) << 1) | (ln >> 5);
    float* outp = z ? PMb : PMa;
    float acc[8][8] = {};
    for (int kc = k0; kc < k0 + 128; kc += 16) {
        #pragma unroll
        for (int j = 0; j < 4; ++j) {
            const int krow = wv * 4 + j;
            __builtin_amdgcn_global_load_lds(
                (const __attribute__((address_space(1))) void*)(M + (size_t)(kc + krow) * PDIM + gsw * 4),
                (__attribute__((address_space(3))) void*)(&Bs[krow][0]),
                16, 0, 0);
        }
        float4 a = *(const float4*)&P[(size_t)(rb + lr) * PDIM + kc + ks];
        As[ks + 0][lr] = a.x;
        As[ks + 1][lr] = a.y;
        As[ks + 2][lr] = a.z;
        As[ks + 3][lr] = a.w;
        __syncthreads();
        #pragma unroll
        for (int k = 0; k < 16; ++k) {
            float4 x0 = *(const float4*)&As[k][ry * 8];
            float4 x1 = *(const float4*)&As[k][ry * 8 + 4];
            float4 y0 = *(const float4*)&Bs[k][rx * 4];
            float4 y1 = *(const float4*)&Bs[k][128 + rx * 4];
            float aa[8] = {x0.x, x0.y, x0.z, x0.w, x1.x, x1.y, x1.z, x1.w};
            float bb[8] = {y0.x, y0.y, y0.z, y0.w, y1.x, y1.y, y1.z, y1.w};
            #pragma unroll
            for (int i = 0; i < 8; ++i)
                #pragma unroll
                for (int j = 0; j < 8; ++j)
                    acc[i][j] = fmaf(aa[i], bb[j], acc[i][j]);
        }
        __syncthreads();
    }
    #pragma unroll
    for (int i = 0; i < 8; ++i) {
        const size_t base = (size_t)(rb + ry * 8 + i) * PDIM + rx * 8;
        *(float4*)&outp[base]     = make_float4(acc[i][0], acc[i][1], acc[i][2], acc[i][3]);
        *(float4*)&outp[base + 4] = make_float4(acc[i][4], acc[i][5], acc[i][6], acc[i][7]);
    }
}

// ============================================================================
// K_wtw: M[256][256] = W^T W  (K=1024). 64x64 tile, 4x4 micro, grid (4,4).
// ============================================================================
__global__ __launch_bounds__(256) void k_wtw(const float* __restrict__ W,
                                             float* __restrict__ M) {
    __shared__ float As[16][64];
    __shared__ float Bs[16][64];
    const int t = threadIdx.x;
    const int tx = t & 15, ty = t >> 4;
    const int ib = blockIdx.x * 64;
    const int jb = blockIdx.y * 64;
    const int sk = t >> 4;
    const int sc = (t & 15) * 4;
    float acc[4][4] = {};
    for (int kc = 0; kc < DIM; kc += 16) {
        float4 a = *(const float4*)&W[(size_t)(kc + sk) * PDIM + ib + sc];
        float4 b = *(const float4*)&W[(size_t)(kc + sk) * PDIM + jb + sc];
        *(float4*)&As[sk][sc] = a;
        *(float4*)&Bs[sk][sc] = b;
        __syncthreads();
        #pragma unroll
        for (int k = 0; k < 16; ++k) {
            float4 a4 = *(const float4*)&As[k][ty * 4];
            float4 b4 = *(const float4*)&Bs[k][tx * 4];
            float aa[4] = {a4.x, a4.y, a4.z, a4.w};
            float bb[4] = {b4.x, b4.y, b4.z, b4.w};
            #pragma unroll
            for (int i = 0; i < 4; ++i)
                #pragma unroll
                for (int j = 0; j < 4; ++j)
                    acc[i][j] = fmaf(aa[i], bb[j], acc[i][j]);
        }
        __syncthreads();
    }
    #pragma unroll
    for (int i = 0; i < 4; ++i)
        #pragma unroll
        for (int j = 0; j < 4; ++j)
            M[(size_t)(ib + ty * 4 + i) * PDIM + jb + tx * 4 + j] = acc[i][j];
}

// xn2[n] = ||x_n + bias||^2   (memory-bound pass over X)
__global__ __launch_bounds__(256) void k_xn2(const float* __restrict__ X,
                                             const float* __restrict__ bias,
                                             float* __restrict__ xn2) {
    const int n = blockIdx.x * 4 + (threadIdx.x >> 6);
    const int lane = threadIdx.x & 63;
    float s = 0.0f;
    #pragma unroll
    for (int i = 0; i < 4; ++i) {
        float4 x = *(const float4*)&X[(size_t)n * DIM + i * 256 + lane * 4];
        float4 b = *(const float4*)&bias[i * 256 + lane * 4];
        float vx = x.x + b.x, vy = x.y + b.y, vz = x.z + b.z, vw = x.w + b.w;
        s = fmaf(vx, vx, s); s = fmaf(vy, vy, s);
        s = fmaf(vz, vz, s); s = fmaf(vw, vw, s);
    }
    #pragma unroll
    for (int o = 1; o < 64; o <<= 1) s += __shfl_xor(s, o);
    if (lane == 0) xn2[n] = s;
}

// rowres[n] = xn2[n] + sum_c P[n][c]*((PMa[n][c]+PMb[n][c]) - 2*P[n][c])
__global__ __launch_bounds__(256) void k_rowres(const float* __restrict__ P,
                                                const float* __restrict__ PMa,
                                                const float* __restrict__ PMb,
                                                const float* __restrict__ xn2,
                                                float* __restrict__ rowres) {
    const int n = blockIdx.x * 4 + (threadIdx.x >> 6);
    const int lane = threadIdx.x & 63;
    float4 p  = *(const float4*)&P[(size_t)n * PDIM + lane * 4];
    float4 pa = *(const float4*)&PMa[(size_t)n * PDIM + lane * 4];
    float4 pb = *(const float4*)&PMb[(size_t)n * PDIM + lane * 4];
    float s = 0.0f;
    s = fmaf(p.x, (pa.x + pb.x) - 2.0f * p.x, s);
    s = fmaf(p.y, (pa.y + pb.y) - 2.0f * p.y, s);
    s = fmaf(p.z, (pa.z + pb.z) - 2.0f * p.z, s);
    s = fmaf(p.w, (pa.w + pb.w) - 2.0f * p.w, s);
    #pragma unroll
    for (int o = 1; o < 64; o <<= 1) s += __shfl_xor(s, o);
    if (lane == 0) rowres[n] = xn2[n] + s;
}

// ============================================================================
// K2: cov += P^T P (fp32, split-K x64, atomicAdd) — tolerant.
// ============================================================================
__global__ __launch_bounds__(256) void k_cov(const float* __restrict__ Pm,
                                             float* __restrict__ cov) {
    __shared__ float As[16][64];
    __shared__ float Bs[16][64];
    const int t = threadIdx.x;
    const int tx = t & 15, ty = t >> 4;
    const int ib = blockIdx.x * 64;
    const int jb = blockIdx.y * 64;
    const int nb = blockIdx.z * 512;
    const int sk = t >> 4;
    const int sc = (t & 15) * 4;
    float acc[4][4] = {};
    for (int kc = 0; kc < 512; kc += 16) {
        float4 a = *(const float4*)&Pm[(size_t)(nb + kc + sk) * PDIM + ib + sc];
        float4 b = *(const float4*)&Pm[(size_t)(nb + kc + sk) * PDIM + jb + sc];
        *(float4*)&As[sk][sc] = a;
        *(float4*)&Bs[sk][sc] = b;
        __syncthreads();
        #pragma unroll
        for (int k = 0; k < 16; ++k) {
            float4 a4 = *(const float4*)&As[k][ty * 4];
            float4 b4 = *(const float4*)&Bs[k][tx * 4];
            float aa[4] = {a4.x, a4.y, a4.z, a4.w};
            float bb[4] = {b4.x, b4.y, b4.z, b4.w};
            #pragma unroll
            for (int i = 0; i < 4; ++i)
                #pragma unroll
                for (int j = 0; j < 4; ++j)
                    acc[i][j] = fmaf(aa[i], bb[j], acc[i][j]);
        }
        __syncthreads();
    }
    #pragma unroll
    for (int i = 0; i < 4; ++i)
        #pragma unroll
        for (int j = 0; j < 4; ++j)
            atomicAdd(&cov[(size_t)(ib + ty * 4 + i) * PDIM + jb + tx * 4 + j], acc[i][j]);
}

__global__ __launch_bounds__(256) void k_covloss(const float* __restrict__ cov,
                                                 float* __restrict__ scal) {
    const int t = threadIdx.x;
    float s = 0.0f;
    for (int e = t; e < PDIM * PDIM; e += 256) {
        int i = e >> 8, j = e & 255;
        float v = cov[e] * (1.0f / 32768.0f) - (i == j ? 1.0f : 0.0f);
        s = fmaf(v, v, s);
    }
    #pragma unroll
    for (int o = 1; o < 64; o <<= 1) s += __shfl_xor(s, o);
    __shared__ float r4[4];
    if ((t & 63) == 0) r4[t >> 6] = s;
    __syncthreads();
    if (t == 0) scal[1] = (r4[0] + r4[1] + r4[2] + r4[3]) * (1.0f / 65536.0f);
}

// l2 sum: scal[0] += sum over rows of sqrt(rowres)
__global__ __launch_bounds__(256) void k_l2(const float* __restrict__ rowres,
                                            float* __restrict__ scal) {
    int r = blockIdx.x * 256 + threadIdx.x;
    float v = sqrtf(rowres[r]);
    #pragma unroll
    for (int o = 1; o < 64; o <<= 1) v += __shfl_xor(v, o);
    if ((threadIdx.x & 63) == 0) atomicAdd(&scal[0], v);
}

// cnorm: numpy pairwise (8-acc) order, exact
__global__ __launch_bounds__(256) void k_cnorm(const float* __restrict__ cbs,
                                               float* __restrict__ cnorm) {
    int c = blockIdx.x * 256 + threadIdx.x;
    const float* p = &cbs[(size_t)c * SECD];
    float a[8];
    #pragma unroll
    for (int j = 0; j < 8; ++j) a[j] = __fmul_rn(p[j], p[j]);
    #pragma unroll
    for (int i = 8; i < 64; i += 8)
        #pragma unroll
        for (int j = 0; j < 8; ++j)
            a[j] = __fadd_rn(a[j], __fmul_rn(p[i + j], p[i + j]));
    float r = __fadd_rn(__fadd_rn(__fadd_rn(a[0], a[1]), __fadd_rn(a[2], a[3])),
                        __fadd_rn(__fadd_rn(a[4], a[5]), __fadd_rn(a[6], a[7])));
    cnorm[c] = r;
}

// ============================================================================
// K4: VQ, exact argmin — the measured-best round-3 structure (262 µs):
// xs/cs staged in LDS, 8x4 micro, sections split across blockIdx.y.
// Distances and lexicographic argmin bit-identical to the round-2 passing
// kernel. qloss d^2 partials -> qpart (combined in k_addpca, which MUST
// run before k_gather).
// ============================================================================
__global__ __launch_bounds__(256) void k_vq(const float* __restrict__ proj,
                                            const float* __restrict__ cbs,
                                            const float* __restrict__ cnorm,
                                            int* __restrict__ widx,
                                            float* __restrict__ out_idx,
                                            float* __restrict__ qpart) {
    __shared__ float xs[64][64];    // xs[k][row]   16 KB
    __shared__ float cs[64][128];   // cs[k][code]  32 KB
    __shared__ float xnorm[64];
    __shared__ int   sidx[64];
    const int t = threadIdx.x;
    const int ry = t >> 5;          // 0..7 -> rows ry*8..+7
    const int tx = t & 31;          // codes tx*4..+3 within ct tile
    const int rb = blockIdx.x * 64;
    const int s  = blockIdx.y;      // section
    const int lr = t >> 2;          // staging row / qloss row 0..63
    const int kq = (t & 3) * 16;    // staging k slab
    const int cr = t >> 1;          // cs staging code 0..127
    const int ko = (t & 1) * 32;    // cs staging k offset

    #pragma unroll
    for (int i = 0; i < 16; i += 4) {
        float4 v = *(const float4*)&proj[(size_t)(rb + lr) * PDIM + s * SECD + kq + i];
        xs[kq + i + 0][lr] = v.x; xs[kq + i + 1][lr] = v.y;
        xs[kq + i + 2][lr] = v.z; xs[kq + i + 3][lr] = v.w;
    }
    __syncthreads();
    if (t < 64) {   // numpy pairwise_sum(64): 8 accumulators, no fma
        float a[8];
        #pragma unroll
        for (int j = 0; j < 8; ++j) { float v = xs[j][t]; a[j] = __fmul_rn(v, v); }
        #pragma unroll
        for (int i = 8; i < 64; i += 8)
            #pragma unroll
            for (int j = 0; j < 8; ++j) {
                float v = xs[i + j][t];
                a[j] = __fadd_rn(a[j], __fmul_rn(v, v));
            }
        xnorm[t] = __fadd_rn(__fadd_rn(__fadd_rn(a[0], a[1]), __fadd_rn(a[2], a[3])),
                             __fadd_rn(__fadd_rn(a[4], a[5]), __fadd_rn(a[6], a[7])));
    }
    float best[8]; int bidx[8];
    #pragma unroll
    for (int i = 0; i < 8; ++i) { best[i] = 3.4e38f; bidx[i] = 0; }

    for (int ct = 0; ct < 8; ++ct) {
        __syncthreads();   // cs reuse guard; publishes xnorm at ct==0
        #pragma unroll
        for (int u = 0; u < 32; u += 4) {
            float4 v = *(const float4*)&cbs[(size_t)(s * NCODE + ct * 128 + cr) * SECD + ko + u];
            cs[ko + u + 0][cr] = v.x; cs[ko + u + 1][cr] = v.y;
            cs[ko + u + 2][cr] = v.z; cs[ko + u + 3][cr] = v.w;
        }
        __syncthreads();
        float4 cn4 = *(const float4*)&cnorm[s * NCODE + ct * 128 + tx * 4];
        float cna[4] = {cn4.x, cn4.y, cn4.z, cn4.w};
        float acc[8][4] = {};
        #pragma unroll 8
        for (int k = 0; k < 64; ++k) {
            float4 x0 = *(const float4*)&xs[k][ry * 8];
            float4 x1 = *(const float4*)&xs[k][ry * 8 + 4];
            float4 b4 = *(const float4*)&cs[k][tx * 4];
            float aa[8] = {x0.x, x0.y, x0.z, x0.w, x1.x, x1.y, x1.z, x1.w};
            float bb[4] = {b4.x, b4.y, b4.z, b4.w};
            #pragma unroll
            for (int i = 0; i < 8; ++i)
                #pragma unroll
                for (int j = 0; j < 4; ++j)
                    acc[i][j] = fmaf(aa[i], bb[j], acc[i][j]);
        }
        #pragma unroll
        for (int i = 0; i < 8; ++i) {
            float xn = xnorm[ry * 8 + i];
            #pragma unroll
            for (int j = 0; j < 4; ++j) {
                float d = __fadd_rn(__fsub_rn(xn, __fmul_rn(2.0f, acc[i][j])), cna[j]);
                int code = ct * 128 + tx * 4 + j;
                if (d < best[i]) { best[i] = d; bidx[i] = code; }
            }
        }
    }
    // lexicographic (dist, idx) min across the 32 tx lanes per row
    #pragma unroll
    for (int i = 0; i < 8; ++i) {
        float d = best[i]; int ix = bidx[i];
        #pragma unroll
        for (int o = 1; o < 32; o <<= 1) {
            float od = __shfl_xor(d, o);
            int   oi = __shfl_xor(ix, o);
            if (od < d || (od == d && oi < ix)) { d = od; ix = oi; }
        }
        if (tx == 0) {
            int row = rb + ry * 8 + i;
            widx[s * NROW + row] = ix;
            out_idx[s * NROW + row] = (float)ix;
            sidx[ry * 8 + i] = ix;
        }
    }
    __syncthreads();
    {   // qloss partial for this section: d^2 per dim
        const float* crow = &cbs[(size_t)(s * NCODE + sidx[lr]) * SECD];
        #pragma unroll
        for (int i = 0; i < 16; i += 4) {
            float4 q = *(const float4*)&crow[kq + i];
            float qq[4] = {q.x, q.y, q.z, q.w};
            float r[4];
            #pragma unroll
            for (int u = 0; u < 4; ++u) {
                float d = qq[u] - xs[kq + i + u][lr];
                r[u] = __fmul_rn(d, d);
            }
            *(float4*)&qpart[((size_t)s * NROW + rb + lr) * SECD + kq + i] =
                make_float4(r[0], r[1], r[2], r[3]);
        }
    }
}

// ============================================================================
// K5: CbU[s][c][d] = sum_k Cb[s][c][k] * W[d][s*64+k]
// ============================================================================
__global__ __launch_bounds__(256) void k_cbu(const float* __restrict__ cbs,
                                             const float* __restrict__ W,
                                             float* __restrict__ cbu) {
    __shared__ float As[16][64];
    __shared__ float Bs[16][64];
    const int t = threadIdx.x;
    const int tx = t & 15, ty = t >> 4;
    const int s = blockIdx.z;
    const int cbase = blockIdx.y * 64;
    const int db = blockIdx.x * 64;
    const int lr = t >> 2;
    const int lk = (t & 3) * 4;
    float acc[4][4] = {};
    for (int kc = 0; kc < SECD; kc += 16) {
        float4 a = *(const float4*)&cbs[(size_t)(s * NCODE + cbase + lr) * SECD + kc + lk];
        float4 b = *(const float4*)&W[(size_t)(db + lr) * PDIM + s * SECD + kc + lk];
        As[lk + 0][lr] = a.x; As[lk + 1][lr] = a.y;
        As[lk + 2][lr] = a.z; As[lk + 3][lr] = a.w;
        Bs[lk + 0][lr] = b.x; Bs[lk + 1][lr] = b.y;
        Bs[lk + 2][lr] = b.z; Bs[lk + 3][lr] = b.w;
        __syncthreads();
        #pragma unroll
        for (int k = 0; k < 16; ++k) {
            float4 a4 = *(const float4*)&As[k][ty * 4];
            float4 b4 = *(const float4*)&Bs[k][tx * 4];
            float aa[4] = {a4.x, a4.y, a4.z, a4.w};
            float bb[4] = {b4.x, b4.y, b4.z, b4.w};
            #pragma unroll
            for (int i = 0; i < 4; ++i)
                #pragma unroll
                for (int j = 0; j < 4; ++j)
                    acc[i][j] = fmaf(aa[i], bb[j], acc[i][j]);
        }
        __syncthreads();
    }
    #pragma unroll
    for (int i = 0; i < 4; ++i) {
        float4 v = make_float4(acc[i][0], acc[i][1], acc[i][2], acc[i][3]);
        *(float4*)&cbu[(size_t)(s * NCODE + cbase + ty * 4 + i) * DIM + db + tx * 4] = v;
    }
}

// K6: out0[n][d] = sum_s CbU[s][idx[s][n]][d] - bias[d]
__global__ __launch_bounds__(256) void k_gather(const float* __restrict__ cbu,
                                                const int* __restrict__ widx,
                                                const float* __restrict__ bias,
                                                float* __restrict__ out0) {
    const int n = blockIdx.x;
    const int d = threadIdx.x * 4;
    int i0 = widx[0 * NROW + n];
    int i1 = widx[1 * NROW + n];
    int i2 = widx[2 * NROW + n];
    int i3 = widx[3 * NROW + n];
    float4 v0 = *(const float4*)&cbu[((size_t)(0 * NCODE + i0)) * DIM + d];
    float4 v1 = *(const float4*)&cbu[((size_t)(1 * NCODE + i1)) * DIM + d];
    float4 v2 = *(const float4*)&cbu[((size_t)(2 * NCODE + i2)) * DIM + d];
    float4 v3 = *(const float4*)&cbu[((size_t)(3 * NCODE + i3)) * DIM + d];
    float4 b = *(const float4*)&bias[d];
    float4 r;
    r.x = v0.x + v1.x + v2.x + v3.x - b.x;
    r.y = v0.y + v1.y + v2.y + v3.y - b.y;
    r.z = v0.z + v1.z + v2.z + v3.z - b.z;
    r.w = v0.w + v1.w + v2.w + v3.w - b.w;
    *(float4*)&out0[(size_t)n * DIM + d] = r;
}

// out1[e] = 0.25*(((q0+q1)+q2)+q3) + pca  — MUST run before k_gather
// (qpart lives inside the out0 region that k_gather overwrites).
__global__ __launch_bounds__(256) void k_addpca(float* __restrict__ out1,
                                                const float* __restrict__ qpart,
                                                const float* __restrict__ scal) {
    float pca = scal[0] * (1.0f / 32768.0f) + scal[1];
    const size_t e = ((size_t)blockIdx.x * 256 + threadIdx.x) * 4;
    float4 a = *(const float4*)&qpart[e];
    float4 b = *(const float4*)&qpart[e + 2097152];
    float4 c = *(const float4*)&qpart[e + 4194304];
    float4 d = *(const float4*)&qpart[e + 6291456];
    float4 r;
    r.x = 0.25f * __fadd_rn(__fadd_rn(__fadd_rn(a.x, b.x), c.x), d.x) + pca;
    r.y = 0.25f * __fadd_rn(__fadd_rn(__fadd_rn(a.y, b.y), c.y), d.y) + pca;
    r.z = 0.25f * __fadd_rn(__fadd_rn(__fadd_rn(a.z, b.z), c.z), d.z) + pca;
    r.w = 0.25f * __fadd_rn(__fadd_rn(__fadd_rn(a.w, b.w), c.w), d.w) + pca;
    *(float4*)&out1[e] = r;
}

__global__ __launch_bounds__(256) void k_tail(const float* __restrict__ cbs,
                                              float* __restrict__ out3,
                                              float* __restrict__ out4) {
    int e = blockIdx.x * 256 + threadIdx.x;
    ((float4*)out3)[e] = ((const float4*)cbs)[e];
    if (e < 4096) out4[e] = 1.0f;
}

extern "C" void kernel_launch(void* const* d_in, const int* in_sizes, int n_in,
                              void* d_out, int out_size, void* d_ws, size_t ws_size,
                              hipStream_t stream) {
    (void)in_sizes; (void)n_in; (void)out_size; (void)ws_size;
    const float* X    = (const float*)d_in[0];   // [32768,1024]
    const float* W    = (const float*)d_in[1];   // [1024,256]
    const float* bias = (const float*)d_in[2];   // [1024]
    const float* cbs  = (const float*)d_in[3];   // [4,1024,64]

    float* out  = (float*)d_out;
    float* out0 = out;                 // quantized [32768,1024]
    float* out1 = out + 33554432;      // qloss [32768,64]
    float* out2 = out + 35651584;      // nn_idx as float [4,32768]
    float* out3 = out + 35782656;      // codebook copy [4096,64]
    float* out4 = out + 36044800;      // cluster_counts ones [4,1024]

    char* ws = (char*)d_ws;
    float* cbu    = (float*)(ws);                  // 16777216 B
    float* rowres = (float*)(ws + 16777216);       //   131072 B
    float* cov    = (float*)(ws + 16908288);       //   262144 B
    float* scal   = (float*)(ws + 17170432);       //       64 B
    float* cnorm  = (float*)(ws + 17170496);       //    16384 B
    int*   widx   = (int*)  (ws + 17186880);       //   524288 B
    float* wtw    = (float*)(ws + 17711168);       //   262144 B (M = W^T W)

    // scratch inside the out0 region (dead before k_gather writes it):
    // p0/proj [0, 8388608), p1 [8388608, 16777216), p2 [16777216, 25165824)
    // PMb at [25165824, 33554432). After k_rowres, p1 region is reused as
    // qpart[4][32768][64]; k_addpca consumes it BEFORE k_gather clobbers out0.
    float* proj  = out0;                 // segment 0 accum -> combined proj
    float* PMa   = out0 + 8388608;       // p1, then PM half A
    float* PMb   = out0 + 25165824;      // PM half B
    float* qpart = out0 + 8388608;       // qloss partials (after PMa is dead)
    // xn2 lives in out1's region (out1 written later by k_addpca)
    float* xn2  = out1;                  // 32768 floats

    // zero cov + scal (contiguous)
    hipMemsetAsync(ws + 16908288, 0, 262144 + 64, stream);

    k_proj    <<<dim3(512, 1, 3), 256, 0, stream>>>(X, W, bias, proj);
    k_comb    <<<8192,            256, 0, stream>>>(proj);
    k_xn2     <<<8192,            256, 0, stream>>>(X, bias, xn2);
    k_wtw     <<<dim3(4, 4),      256, 0, stream>>>(W, wtw);
    k_cov     <<<dim3(4, 4, 64),  256, 0, stream>>>(proj, cov);
    k_covloss <<<1,               256, 0, stream>>>(cov, scal);
    k_pm      <<<dim3(512, 1, 2), 256, 0, stream>>>(proj, wtw, PMa, PMb);
    k_rowres  <<<8192,            256, 0, stream>>>(proj, PMa, PMb, xn2, rowres);
    k_l2      <<<128,             256, 0, stream>>>(rowres, scal);
    k_cnorm   <<<16,              256, 0, stream>>>(cbs, cnorm);
    k_vq      <<<dim3(512, 4),    256, 0, stream>>>(proj, cbs, cnorm, widx, out2, qpart);
    k_addpca  <<<2048,            256, 0, stream>>>(out1, qpart, scal);   // before k_gather!
    k_cbu     <<<dim3(16, 16, 4), 256, 0, stream>>>(cbs, W, cbu);
    k_gather  <<<32768,           256, 0, stream>>>(cbu, widx, bias, out0);
    k_tail    <<<256,             256, 0, stream>>>(cbs, out3, out4);
}

// Round 15
// 1022.451 us; speedup vs baseline: 1.3349x; 1.0456x over previous
//
#include <hip/hip_runtime.h>
#include <math.h>

#define NROW 32768
#define DIM  1024
#define PDIM 256
#define NSEC 4
#define NCODE 1024
#define SECD 64

// ============================================================================
// K1: proj = (X + bias) @ W, exact OpenBLAS order, K split at 384/768 into
// 3 independent fmaf-chain segments (blockIdx.z); rn-add folds happen in
// k_comb as ((s0+s1)+s2). 64x256 tile, 256 thr, 8x8 micro, 4 waves/SIMD.
// ============================================================================
__global__ __launch_bounds__(256, 4) void k_proj(const float* __restrict__ X,
                                                 const float* __restrict__ W,
                                                 const float* __restrict__ bias,
                                                 float* __restrict__ p0) {
    __shared__ __align__(16) float As[16][68];   // As[k][row], pad 68: writes 2-way (free)
    __shared__ __align__(16) float Bs[16][256];  // linear (global_load_lds dest)
    const int t  = threadIdx.x;
    const int ry = t >> 5;            // 0..7 -> rows ry*8..+7
    const int rx = t & 31;            // col-group -> cols rx*8..+7
    const int rb = blockIdx.x * 64;
    const int z  = blockIdx.z;
    const int k0 = z * 384;
    const int kn = (z == 2) ? 256 : 384;
    const int lr = t >> 2;            // A-stage row 0..63
    const int ks = (t & 3) * 4;       // A-stage k offset
    const int wv = t >> 6;
    const int ln = t & 63;
    // lane ln writes LDS granule ln; source granule: ln<32 -> 2*ln, else 2*(ln-32)+1
    const int gsw = ((ln & 31) << 1) | (ln >> 5);
    float* outp = p0 + (size_t)z * ((size_t)NROW * PDIM);
    float acc[8][8] = {};
    for (int kc = k0; kc < k0 + kn; kc += 16) {
        #pragma unroll
        for (int j = 0; j < 4; ++j) {
            const int krow = wv * 4 + j;
            __builtin_amdgcn_global_load_lds(
                (const __attribute__((address_space(1))) void*)(W + (size_t)(kc + krow) * PDIM + gsw * 4),
                (__attribute__((address_space(3))) void*)(&Bs[krow][0]),
                16, 0, 0);
        }
        float4 a = *(const float4*)&X[(size_t)(rb + lr) * DIM + kc + ks];
        float4 c = *(const float4*)&bias[kc + ks];
        As[ks + 0][lr] = a.x + c.x;
        As[ks + 1][lr] = a.y + c.y;
        As[ks + 2][lr] = a.z + c.z;
        As[ks + 3][lr] = a.w + c.w;
        __syncthreads();   // drains vmcnt (global_load_lds) + lgkmcnt (ds writes)
        #pragma unroll
        for (int k = 0; k < 16; ++k) {
            float4 x0 = *(const float4*)&As[k][ry * 8];
            float4 x1 = *(const float4*)&As[k][ry * 8 + 4];
            float4 y0 = *(const float4*)&Bs[k][rx * 4];         // cols rx*8..+3
            float4 y1 = *(const float4*)&Bs[k][128 + rx * 4];   // cols rx*8+4..+7
            float aa[8] = {x0.x, x0.y, x0.z, x0.w, x1.x, x1.y, x1.z, x1.w};
            float bb[8] = {y0.x, y0.y, y0.z, y0.w, y1.x, y1.y, y1.z, y1.w};
            #pragma unroll
            for (int i = 0; i < 8; ++i)
                #pragma unroll
                for (int j = 0; j < 8; ++j)
                    acc[i][j] = fmaf(aa[i], bb[j], acc[i][j]);
        }
        __syncthreads();
    }
    #pragma unroll
    for (int i = 0; i < 8; ++i) {
        const size_t base = (size_t)(rb + ry * 8 + i) * PDIM + rx * 8;
        *(float4*)&outp[base]     = make_float4(acc[i][0], acc[i][1], acc[i][2], acc[i][3]);
        *(float4*)&outp[base + 4] = make_float4(acc[i][4], acc[i][5], acc[i][6], acc[i][7]);
    }
}

// proj[i] = ((s0 + s1) + s2), rn adds — bit-identical to the original fold.
__global__ __launch_bounds__(256) void k_comb(float* __restrict__ p) {
    const size_t i = ((size_t)blockIdx.x * 256 + threadIdx.x) * 4;
    float4 a = *(const float4*)&p[i];
    float4 b = *(const float4*)&p[i + 8388608];
    float4 c = *(const float4*)&p[i + 16777216];
    float4 r;
    r.x = __fadd_rn(__fadd_rn(a.x, b.x), c.x);
    r.y = __fadd_rn(__fadd_rn(a.y, b.y), c.y);
    r.z = __fadd_rn(__fadd_rn(a.z, b.z), c.z);
    r.w = __fadd_rn(__fadd_rn(a.w, b.w), c.w);
    *(float4*)&p[i] = r;
}

// ============================================================================
// K_pm: PM = proj @ M (M = W^T W), tolerant numerics. Same 64x256 template,
// K=256 split into 2 z-halves; halves summed inside k_rowres (no combine).
// ============================================================================
__global__ __launch_bounds__(256, 4) void k_pm(const float* __restrict__ P,
                                               const float* __restrict__ M,
                                               float* __restrict__ PMa,
                                               float* __restrict__ PMb) {
    __shared__ __align__(16) float As[16][68];
    __shared__ __align__(16) float Bs[16][256];
    const int t  = threadIdx.x;
    const int ry = t >> 5;
    const int rx = t & 31;
    const int rb = blockIdx.x * 64;
    const int z  = blockIdx.z;
    const int k0 = z * 128;
    const int lr = t >> 2;
    const int ks = (t & 3) * 4;
    const int wv = t >> 6;
    const int ln = t & 63;
    const int gsw = ((ln & 31) << 1) | (ln >> 5);
    float* outp = z ? PMb : PMa;
    float acc[8][8] = {};
    for (int kc = k0; kc < k0 + 128; kc += 16) {
        #pragma unroll
        for (int j = 0; j < 4; ++j) {
            const int krow = wv * 4 + j;
            __builtin_amdgcn_global_load_lds(
                (const __attribute__((address_space(1))) void*)(M + (size_t)(kc + krow) * PDIM + gsw * 4),
                (__attribute__((address_space(3))) void*)(&Bs[krow][0]),
                16, 0, 0);
        }
        float4 a = *(const float4*)&P[(size_t)(rb + lr) * PDIM + kc + ks];
        As[ks + 0][lr] = a.x;
        As[ks + 1][lr] = a.y;
        As[ks + 2][lr] = a.z;
        As[ks + 3][lr] = a.w;
        __syncthreads();
        #pragma unroll
        for (int k = 0; k < 16; ++k) {
            float4 x0 = *(const float4*)&As[k][ry * 8];
            float4 x1 = *(const float4*)&As[k][ry * 8 + 4];
            float4 y0 = *(const float4*)&Bs[k][rx * 4];
            float4 y1 = *(const float4*)&Bs[k][128 + rx * 4];
            float aa[8] = {x0.x, x0.y, x0.z, x0.w, x1.x, x1.y, x1.z, x1.w};
            float bb[8] = {y0.x, y0.y, y0.z, y0.w, y1.x, y1.y, y1.z, y1.w};
            #pragma unroll
            for (int i = 0; i < 8; ++i)
                #pragma unroll
                for (int j = 0; j < 8; ++j)
                    acc[i][j] = fmaf(aa[i], bb[j], acc[i][j]);
        }
        __syncthreads();
    }
    #pragma unroll
    for (int i = 0; i < 8; ++i) {
        const size_t base = (size_t)(rb + ry * 8 + i) * PDIM + rx * 8;
        *(float4*)&outp[base]     = make_float4(acc[i][0], acc[i][1], acc[i][2], acc[i][3]);
        *(float4*)&outp[base + 4] = make_float4(acc[i][4], acc[i][5], acc[i][6], acc[i][7]);
    }
}

// ============================================================================
// K_wtw: M[256][256] = W^T W  (K=1024). 64x64 tile, 4x4 micro, grid (4,4).
// ============================================================================
__global__ __launch_bounds__(256) void k_wtw(const float* __restrict__ W,
                                             float* __restrict__ M) {
    __shared__ float As[16][64];
    __shared__ float Bs[16][64];
    const int t = threadIdx.x;
    const int tx = t & 15, ty = t >> 4;
    const int ib = blockIdx.x * 64;
    const int jb = blockIdx.y * 64;
    const int sk = t >> 4;
    const int sc = (t & 15) * 4;
    float acc[4][4] = {};
    for (int kc = 0; kc < DIM; kc += 16) {
        float4 a = *(const float4*)&W[(size_t)(kc + sk) * PDIM + ib + sc];
        float4 b = *(const float4*)&W[(size_t)(kc + sk) * PDIM + jb + sc];
        *(float4*)&As[sk][sc] = a;
        *(float4*)&Bs[sk][sc] = b;
        __syncthreads();
        #pragma unroll
        for (int k = 0; k < 16; ++k) {
            float4 a4 = *(const float4*)&As[k][ty * 4];
            float4 b4 = *(const float4*)&Bs[k][tx * 4];
            float aa[4] = {a4.x, a4.y, a4.z, a4.w};
            float bb[4] = {b4.x, b4.y, b4.z, b4.w};
            #pragma unroll
            for (int i = 0; i < 4; ++i)
                #pragma unroll
                for (int j = 0; j < 4; ++j)
                    acc[i][j] = fmaf(aa[i], bb[j], acc[i][j]);
        }
        __syncthreads();
    }
    #pragma unroll
    for (int i = 0; i < 4; ++i)
        #pragma unroll
        for (int j = 0; j < 4; ++j)
            M[(size_t)(ib + ty * 4 + i) * PDIM + jb + tx * 4 + j] = acc[i][j];
}

// xn2[n] = ||x_n + bias||^2   (memory-bound pass over X)
__global__ __launch_bounds__(256) void k_xn2(const float* __restrict__ X,
                                             const float* __restrict__ bias,
                                             float* __restrict__ xn2) {
    const int n = blockIdx.x * 4 + (threadIdx.x >> 6);
    const int lane = threadIdx.x & 63;
    float s = 0.0f;
    #pragma unroll
    for (int i = 0; i < 4; ++i) {
        float4 x = *(const float4*)&X[(size_t)n * DIM + i * 256 + lane * 4];
        float4 b = *(const float4*)&bias[i * 256 + lane * 4];
        float vx = x.x + b.x, vy = x.y + b.y, vz = x.z + b.z, vw = x.w + b.w;
        s = fmaf(vx, vx, s); s = fmaf(vy, vy, s);
        s = fmaf(vz, vz, s); s = fmaf(vw, vw, s);
    }
    #pragma unroll
    for (int o = 1; o < 64; o <<= 1) s += __shfl_xor(s, o);
    if (lane == 0) xn2[n] = s;
}

// rowres[n] = xn2[n] + sum_c P[n][c]*((PMa[n][c]+PMb[n][c]) - 2*P[n][c])
__global__ __launch_bounds__(256) void k_rowres(const float* __restrict__ P,
                                                const float* __restrict__ PMa,
                                                const float* __restrict__ PMb,
                                                const float* __restrict__ xn2,
                                                float* __restrict__ rowres) {
    const int n = blockIdx.x * 4 + (threadIdx.x >> 6);
    const int lane = threadIdx.x & 63;
    float4 p  = *(const float4*)&P[(size_t)n * PDIM + lane * 4];
    float4 pa = *(const float4*)&PMa[(size_t)n * PDIM + lane * 4];
    float4 pb = *(const float4*)&PMb[(size_t)n * PDIM + lane * 4];
    float s = 0.0f;
    s = fmaf(p.x, (pa.x + pb.x) - 2.0f * p.x, s);
    s = fmaf(p.y, (pa.y + pb.y) - 2.0f * p.y, s);
    s = fmaf(p.z, (pa.z + pb.z) - 2.0f * p.z, s);
    s = fmaf(p.w, (pa.w + pb.w) - 2.0f * p.w, s);
    #pragma unroll
    for (int o = 1; o < 64; o <<= 1) s += __shfl_xor(s, o);
    if (lane == 0) rowres[n] = xn2[n] + s;
}

// ============================================================================
// K2: cov += P^T P (fp32, split-K x64, atomicAdd) — tolerant.
// ============================================================================
__global__ __launch_bounds__(256) void k_cov(const float* __restrict__ Pm,
                                             float* __restrict__ cov) {
    __shared__ float As[16][64];
    __shared__ float Bs[16][64];
    const int t = threadIdx.x;
    const int tx = t & 15, ty = t >> 4;
    const int ib = blockIdx.x * 64;
    const int jb = blockIdx.y * 64;
    const int nb = blockIdx.z * 512;
    const int sk = t >> 4;
    const int sc = (t & 15) * 4;
    float acc[4][4] = {};
    for (int kc = 0; kc < 512; kc += 16) {
        float4 a = *(const float4*)&Pm[(size_t)(nb + kc + sk) * PDIM + ib + sc];
        float4 b = *(const float4*)&Pm[(size_t)(nb + kc + sk) * PDIM + jb + sc];
        *(float4*)&As[sk][sc] = a;
        *(float4*)&Bs[sk][sc] = b;
        __syncthreads();
        #pragma unroll
        for (int k = 0; k < 16; ++k) {
            float4 a4 = *(const float4*)&As[k][ty * 4];
            float4 b4 = *(const float4*)&Bs[k][tx * 4];
            float aa[4] = {a4.x, a4.y, a4.z, a4.w};
            float bb[4] = {b4.x, b4.y, b4.z, b4.w};
            #pragma unroll
            for (int i = 0; i < 4; ++i)
                #pragma unroll
                for (int j = 0; j < 4; ++j)
                    acc[i][j] = fmaf(aa[i], bb[j], acc[i][j]);
        }
        __syncthreads();
    }
    #pragma unroll
    for (int i = 0; i < 4; ++i)
        #pragma unroll
        for (int j = 0; j < 4; ++j)
            atomicAdd(&cov[(size_t)(ib + ty * 4 + i) * PDIM + jb + tx * 4 + j], acc[i][j]);
}

__global__ __launch_bounds__(256) void k_covloss(const float* __restrict__ cov,
                                                 float* __restrict__ scal) {
    const int t = threadIdx.x;
    float s = 0.0f;
    for (int e = t; e < PDIM * PDIM; e += 256) {
        int i = e >> 8, j = e & 255;
        float v = cov[e] * (1.0f / 32768.0f) - (i == j ? 1.0f : 0.0f);
        s = fmaf(v, v, s);
    }
    #pragma unroll
    for (int o = 1; o < 64; o <<= 1) s += __shfl_xor(s, o);
    __shared__ float r4[4];
    if ((t & 63) == 0) r4[t >> 6] = s;
    __syncthreads();
    if (t == 0) scal[1] = (r4[0] + r4[1] + r4[2] + r4[3]) * (1.0f / 65536.0f);
}

// l2 sum: scal[0] += sum over rows of sqrt(rowres)
__global__ __launch_bounds__(256) void k_l2(const float* __restrict__ rowres,
                                            float* __restrict__ scal) {
    int r = blockIdx.x * 256 + threadIdx.x;
    float v = sqrtf(rowres[r]);
    #pragma unroll
    for (int o = 1; o < 64; o <<= 1) v += __shfl_xor(v, o);
    if ((threadIdx.x & 63) == 0) atomicAdd(&scal[0], v);
}

// cnorm: numpy pairwise (8-acc) order, exact
__global__ __launch_bounds__(256) void k_cnorm(const float* __restrict__ cbs,
                                               float* __restrict__ cnorm) {
    int c = blockIdx.x * 256 + threadIdx.x;
    const float* p = &cbs[(size_t)c * SECD];
    float a[8];
    #pragma unroll
    for (int j = 0; j < 8; ++j) a[j] = __fmul_rn(p[j], p[j]);
    #pragma unroll
    for (int i = 8; i < 64; i += 8)
        #pragma unroll
        for (int j = 0; j < 8; ++j)
            a[j] = __fadd_rn(a[j], __fmul_rn(p[i + j], p[i + j]));
    float r = __fadd_rn(__fadd_rn(__fadd_rn(a[0], a[1]), __fadd_rn(a[2], a[3])),
                        __fadd_rn(__fadd_rn(a[4], a[5]), __fadd_rn(a[6], a[7])));
    cnorm[c] = r;
}

// ============================================================================
// K4: VQ, exact argmin. 128 rows x 128 codes per tile, 8x8 micro (ry=t>>4
// owns 8 rows, cx=t&15 owns 8 codes): 2x fma per LDS byte and per barrier
// vs the 8x4 version. xs reads are 16-lane broadcasts. Distance fmaf chain
// per (row,code) k-ascending and argmin semantics (thread-local first-min
// over disjoint code sets, then 16-lane lexicographic (d,idx) min) are
// bit-identical to the passing kernel. qloss d^2 -> qpart (k_addpca before
// k_gather).
// ============================================================================
__global__ __launch_bounds__(256) void k_vq(const float* __restrict__ proj,
                                            const float* __restrict__ cbs,
                                            const float* __restrict__ cnorm,
                                            int* __restrict__ widx,
                                            float* __restrict__ out_idx,
                                            float* __restrict__ qpart) {
    __shared__ float xs[64][128];   // xs[k][row]   32 KB
    __shared__ float cs[64][128];   // cs[k][code]  32 KB
    __shared__ float xnorm[128];
    __shared__ int   sidx[128];
    const int t = threadIdx.x;
    const int ry = t >> 4;          // 0..15 -> rows ry*8..+7
    const int cx = t & 15;          // codes cx*8..+7 within ct tile
    const int rb = blockIdx.x * 128;
    const int s  = blockIdx.y;      // section
    const int xr = t >> 1;          // staging/qloss row 0..127
    const int kq = (t & 1) * 32;    // staging k slab
    const int cr = t >> 1;          // cs staging code 0..127
    const int ko = (t & 1) * 32;    // cs staging k offset

    #pragma unroll
    for (int i = 0; i < 32; i += 4) {
        float4 v = *(const float4*)&proj[(size_t)(rb + xr) * PDIM + s * SECD + kq + i];
        xs[kq + i + 0][xr] = v.x; xs[kq + i + 1][xr] = v.y;
        xs[kq + i + 2][xr] = v.z; xs[kq + i + 3][xr] = v.w;
    }
    __syncthreads();
    if (t < 128) {   // numpy pairwise_sum(64): 8 accumulators, no fma
        float a[8];
        #pragma unroll
        for (int j = 0; j < 8; ++j) { float v = xs[j][t]; a[j] = __fmul_rn(v, v); }
        #pragma unroll
        for (int i = 8; i < 64; i += 8)
            #pragma unroll
            for (int j = 0; j < 8; ++j) {
                float v = xs[i + j][t];
                a[j] = __fadd_rn(a[j], __fmul_rn(v, v));
            }
        xnorm[t] = __fadd_rn(__fadd_rn(__fadd_rn(a[0], a[1]), __fadd_rn(a[2], a[3])),
                             __fadd_rn(__fadd_rn(a[4], a[5]), __fadd_rn(a[6], a[7])));
    }
    float best[8]; int bidx[8];
    #pragma unroll
    for (int i = 0; i < 8; ++i) { best[i] = 3.4e38f; bidx[i] = 0; }

    for (int ct = 0; ct < 8; ++ct) {
        __syncthreads();   // cs reuse guard; publishes xnorm at ct==0
        #pragma unroll
        for (int u = 0; u < 32; u += 4) {
            float4 v = *(const float4*)&cbs[(size_t)(s * NCODE + ct * 128 + cr) * SECD + ko + u];
            cs[ko + u + 0][cr] = v.x; cs[ko + u + 1][cr] = v.y;
            cs[ko + u + 2][cr] = v.z; cs[ko + u + 3][cr] = v.w;
        }
        __syncthreads();
        float4 cn4a = *(const float4*)&cnorm[s * NCODE + ct * 128 + cx * 8];
        float4 cn4b = *(const float4*)&cnorm[s * NCODE + ct * 128 + cx * 8 + 4];
        float cna[8] = {cn4a.x, cn4a.y, cn4a.z, cn4a.w, cn4b.x, cn4b.y, cn4b.z, cn4b.w};
        float acc[8][8] = {};
        #pragma unroll 4
        for (int k = 0; k < 64; ++k) {
            float4 x0 = *(const float4*)&xs[k][ry * 8];
            float4 x1 = *(const float4*)&xs[k][ry * 8 + 4];
            float4 c0 = *(const float4*)&cs[k][cx * 8];
            float4 c1 = *(const float4*)&cs[k][cx * 8 + 4];
            float aa[8] = {x0.x, x0.y, x0.z, x0.w, x1.x, x1.y, x1.z, x1.w};
            float bb[8] = {c0.x, c0.y, c0.z, c0.w, c1.x, c1.y, c1.z, c1.w};
            #pragma unroll
            for (int i = 0; i < 8; ++i)
                #pragma unroll
                for (int j = 0; j < 8; ++j)
                    acc[i][j] = fmaf(aa[i], bb[j], acc[i][j]);
        }
        #pragma unroll
        for (int i = 0; i < 8; ++i) {
            float xn = xnorm[ry * 8 + i];
            #pragma unroll
            for (int j = 0; j < 8; ++j) {
                float d = __fadd_rn(__fsub_rn(xn, __fmul_rn(2.0f, acc[i][j])), cna[j]);
                int code = ct * 128 + cx * 8 + j;
                if (d < best[i]) { best[i] = d; bidx[i] = code; }
            }
        }
    }
    // lexicographic (dist, idx) min across the 16 cx lanes per row group
    #pragma unroll
    for (int i = 0; i < 8; ++i) {
        float d = best[i]; int ix = bidx[i];
        #pragma unroll
        for (int o = 1; o < 16; o <<= 1) {
            float od = __shfl_xor(d, o);
            int   oi = __shfl_xor(ix, o);
            if (od < d || (od == d && oi < ix)) { d = od; ix = oi; }
        }
        if (cx == 0) {
            int row = rb + ry * 8 + i;
            widx[s * NROW + row] = ix;
            out_idx[s * NROW + row] = (float)ix;
            sidx[ry * 8 + i] = ix;
        }
    }
    __syncthreads();
    {   // qloss partial for this section: d^2 per dim
        const float* crow = &cbs[(size_t)(s * NCODE + sidx[xr]) * SECD];
        #pragma unroll
        for (int i = 0; i < 32; i += 4) {
            float4 q = *(const float4*)&crow[kq + i];
            float qq[4] = {q.x, q.y, q.z, q.w};
            float r[4];
            #pragma unroll
            for (int u = 0; u < 4; ++u) {
                float d = qq[u] - xs[kq + i + u][xr];
                r[u] = __fmul_rn(d, d);
            }
            *(float4*)&qpart[((size_t)s * NROW + rb + xr) * SECD + kq + i] =
                make_float4(r[0], r[1], r[2], r[3]);
        }
    }
}

// ============================================================================
// K5: CbU[s][c][d] = sum_k Cb[s][c][k] * W[d][s*64+k]
// ============================================================================
__global__ __launch_bounds__(256) void k_cbu(const float* __restrict__ cbs,
                                             const float* __restrict__ W,
                                             float* __restrict__ cbu) {
    __shared__ float As[16][64];
    __shared__ float Bs[16][64];
    const int t = threadIdx.x;
    const int tx = t & 15, ty = t >> 4;
    const int s = blockIdx.z;
    const int cbase = blockIdx.y * 64;
    const int db = blockIdx.x * 64;
    const int lr = t >> 2;
    const int lk = (t & 3) * 4;
    float acc[4][4] = {};
    for (int kc = 0; kc < SECD; kc += 16) {
        float4 a = *(const float4*)&cbs[(size_t)(s * NCODE + cbase + lr) * SECD + kc + lk];
        float4 b = *(const float4*)&W[(size_t)(db + lr) * PDIM + s * SECD + kc + lk];
        As[lk + 0][lr] = a.x; As[lk + 1][lr] = a.y;
        As[lk + 2][lr] = a.z; As[lk + 3][lr] = a.w;
        Bs[lk + 0][lr] = b.x; Bs[lk + 1][lr] = b.y;
        Bs[lk + 2][lr] = b.z; Bs[lk + 3][lr] = b.w;
        __syncthreads();
        #pragma unroll
        for (int k = 0; k < 16; ++k) {
            float4 a4 = *(const float4*)&As[k][ty * 4];
            float4 b4 = *(const float4*)&Bs[k][tx * 4];
            float aa[4] = {a4.x, a4.y, a4.z, a4.w};
            float bb[4] = {b4.x, b4.y, b4.z, b4.w};
            #pragma unroll
            for (int i = 0; i < 4; ++i)
                #pragma unroll
                for (int j = 0; j < 4; ++j)
                    acc[i][j] = fmaf(aa[i], bb[j], acc[i][j]);
        }
        __syncthreads();
    }
    #pragma unroll
    for (int i = 0; i < 4; ++i) {
        float4 v = make_float4(acc[i][0], acc[i][1], acc[i][2], acc[i][3]);
        *(float4*)&cbu[(size_t)(s * NCODE + cbase + ty * 4 + i) * DIM + db + tx * 4] = v;
    }
}

// K6: out0[n][d] = sum_s CbU[s][idx[s][n]][d] - bias[d]
__global__ __launch_bounds__(256) void k_gather(const float* __restrict__ cbu,
                                                const int* __restrict__ widx,
                                                const float* __restrict__ bias,
                                                float* __restrict__ out0) {
    const int n = blockIdx.x;
    const int d = threadIdx.x * 4;
    int i0 = widx[0 * NROW + n];
    int i1 = widx[1 * NROW + n];
    int i2 = widx[2 * NROW + n];
    int i3 = widx[3 * NROW + n];
    float4 v0 = *(const float4*)&cbu[((size_t)(0 * NCODE + i0)) * DIM + d];
    float4 v1 = *(const float4*)&cbu[((size_t)(1 * NCODE + i1)) * DIM + d];
    float4 v2 = *(const float4*)&cbu[((size_t)(2 * NCODE + i2)) * DIM + d];
    float4 v3 = *(const float4*)&cbu[((size_t)(3 * NCODE + i3)) * DIM + d];
    float4 b = *(const float4*)&bias[d];
    float4 r;
    r.x = v0.x + v1.x + v2.x + v3.x - b.x;
    r.y = v0.y + v1.y + v2.y + v3.y - b.y;
    r.z = v0.z + v1.z + v2.z + v3.z - b.z;
    r.w = v0.w + v1.w + v2.w + v3.w - b.w;
    *(float4*)&out0[(size_t)n * DIM + d] = r;
}

// out1[e] = 0.25*(((q0+q1)+q2)+q3) + pca  — MUST run before k_gather
// (qpart lives inside the out0 region that k_gather overwrites).
__global__ __launch_bounds__(256) void k_addpca(float* __restrict__ out1,
                                                const float* __restrict__ qpart,
                                                const float* __restrict__ scal) {
    float pca = scal[0] * (1.0f / 32768.0f) + scal[1];
    const size_t e = ((size_t)blockIdx.x * 256 + threadIdx.x) * 4;
    float4 a = *(const float4*)&qpart[e];
    float4 b = *(const float4*)&qpart[e + 2097152];
    float4 c = *(const float4*)&qpart[e + 4194304];
    float4 d = *(const float4*)&qpart[e + 6291456];
    float4 r;
    r.x = 0.25f * __fadd_rn(__fadd_rn(__fadd_rn(a.x, b.x), c.x), d.x) + pca;
    r.y = 0.25f * __fadd_rn(__fadd_rn(__fadd_rn(a.y, b.y), c.y), d.y) + pca;
    r.z = 0.25f * __fadd_rn(__fadd_rn(__fadd_rn(a.z, b.z), c.z), d.z) + pca;
    r.w = 0.25f * __fadd_rn(__fadd_rn(__fadd_rn(a.w, b.w), c.w), d.w) + pca;
    *(float4*)&out1[e] = r;
}

__global__ __launch_bounds__(256) void k_tail(const float* __restrict__ cbs,
                                              float* __restrict__ out3,
                                              float* __restrict__ out4) {
    int e = blockIdx.x * 256 + threadIdx.x;
    ((float4*)out3)[e] = ((const float4*)cbs)[e];
    if (e < 4096) out4[e] = 1.0f;
}

extern "C" void kernel_launch(void* const* d_in, const int* in_sizes, int n_in,
                              void* d_out, int out_size, void* d_ws, size_t ws_size,
                              hipStream_t stream) {
    (void)in_sizes; (void)n_in; (void)out_size; (void)ws_size;
    const float* X    = (const float*)d_in[0];   // [32768,1024]
    const float* W    = (const float*)d_in[1];   // [1024,256]
    const float* bias = (const float*)d_in[2];   // [1024]
    const float* cbs  = (const float*)d_in[3];   // [4,1024,64]

    float* out  = (float*)d_out;
    float* out0 = out;                 // quantized [32768,1024]
    float* out1 = out + 33554432;      // qloss [32768,64]
    float* out2 = out + 35651584;      // nn_idx as float [4,32768]
    float* out3 = out + 35782656;      // codebook copy [4096,64]
    float* out4 = out + 36044800;      // cluster_counts ones [4,1024]

    char* ws = (char*)d_ws;
    float* cbu    = (float*)(ws);                  // 16777216 B
    float* rowres = (float*)(ws + 16777216);       //   131072 B
    float* cov    = (float*)(ws + 16908288);       //   262144 B
    float* scal   = (float*)(ws + 17170432);       //       64 B
    float* cnorm  = (float*)(ws + 17170496);       //    16384 B
    int*   widx   = (int*)  (ws + 17186880);       //   524288 B
    float* wtw    = (float*)(ws + 17711168);       //   262144 B (M = W^T W)

    // scratch inside the out0 region (dead before k_gather writes it):
    // p0/proj [0, 8388608), p1 [8388608, 16777216), p2 [16777216, 25165824)
    // PMb at [25165824, 33554432). After k_rowres, p1 region is reused as
    // qpart[4][32768][64]; k_addpca consumes it BEFORE k_gather clobbers out0.
    float* proj  = out0;                 // segment 0 accum -> combined proj
    float* PMa   = out0 + 8388608;       // p1, then PM half A
    float* PMb   = out0 + 25165824;      // PM half B
    float* qpart = out0 + 8388608;       // qloss partials (after PMa is dead)
    // xn2 lives in out1's region (out1 written later by k_addpca)
    float* xn2  = out1;                  // 32768 floats

    // zero cov + scal (contiguous)
    hipMemsetAsync(ws + 16908288, 0, 262144 + 64, stream);

    k_proj    <<<dim3(512, 1, 3), 256, 0, stream>>>(X, W, bias, proj);
    k_comb    <<<8192,            256, 0, stream>>>(proj);
    k_xn2     <<<8192,            256, 0, stream>>>(X, bias, xn2);
    k_wtw     <<<dim3(4, 4),      256, 0, stream>>>(W, wtw);
    k_cov     <<<dim3(4, 4, 64),  256, 0, stream>>>(proj, cov);
    k_covloss <<<1,               256, 0, stream>>>(cov, scal);
    k_pm      <<<dim3(512, 1, 2), 256, 0, stream>>>(proj, wtw, PMa, PMb);
    k_rowres  <<<8192,            256, 0, stream>>>(proj, PMa, PMb, xn2, rowres);
    k_l2      <<<128,             256, 0, stream>>>(rowres, scal);
    k_cnorm   <<<16,              256, 0, stream>>>(cbs, cnorm);
    k_vq      <<<dim3(256, 4),    256, 0, stream>>>(proj, cbs, cnorm, widx, out2, qpart);
    k_addpca  <<<2048,            256, 0, stream>>>(out1, qpart, scal);   // before k_gather!
    k_cbu     <<<dim3(16, 16, 4), 256, 0, stream>>>(cbs, W, cbu);
    k_gather  <<<32768,           256, 0, stream>>>(cbu, widx, bias, out0);
    k_tail    <<<256,             256, 0, stream>>>(cbs, out3, out4);
}